// Round 1
// baseline (1028.778 us; speedup 1.0000x reference)
//
#include <hip/hip_runtime.h>
#include <hip/hip_bf16.h>
#include <cstdint>

#define BATCH  32768
#define DMODEL 4096
#define KSUB   64

using bf16x8 = __attribute__((ext_vector_type(8))) short;   // 8 bf16 (4 VGPRs)
using f32x4  = __attribute__((ext_vector_type(4))) float;   // 4 fp32

static __device__ __forceinline__ short f2bf(float f) {
    // round-to-nearest-even f32 -> bf16 (inputs are finite normals)
    unsigned u = __float_as_uint(f);
    unsigned r = (u + 0x7FFFu + ((u >> 16) & 1u)) >> 16;
    return (short)r;
}

// ---------------------------------------------------------------------------
// K0: block k (64 blocks) builds UT[k][d] = bf16(U[d][k]) and exact f32
//     rm[k] = sum_d mu[d]*U[d][k],  rt[k] = sum_d target[d]*U[d][k]
// ---------------------------------------------------------------------------
__global__ __launch_bounds__(256) void k0_setup(
        const float* __restrict__ U, const float* __restrict__ mu,
        const float* __restrict__ tg, short* __restrict__ ut,
        float* __restrict__ rm, float* __restrict__ rt) {
    int k = blockIdx.x;      // 0..63
    int t = threadIdx.x;     // 0..255
    float pm = 0.f, pt = 0.f;
    for (int d = t; d < DMODEL; d += 256) {
        float u = U[(size_t)d * KSUB + k];
        ut[(size_t)k * DMODEL + d] = f2bf(u);   // coalesced 2B stores
        pm += mu[d] * u;
        pt += tg[d] * u;
    }
    __shared__ float sm[256], st[256];
    sm[t] = pm; st[t] = pt;
    __syncthreads();
    for (int s = 128; s > 0; s >>= 1) {
        if (t < s) { sm[t] += sm[t + s]; st[t] += st[t + s]; }
        __syncthreads();
    }
    if (t == 0) { rm[k] = sm[0]; rt[k] = st[0]; }
}

// ---------------------------------------------------------------------------
// K1: r0(32768x64) = x(32768x4096) @ U(4096x64), bf16 MFMA 16x16x32.
// One wave per 16-row m-tile; N=64 -> 4 n-tiles; K-loop in chunks of 32.
// A frags straight from global (8 contiguous f32 -> bf16x8 per lane);
// B frags from bf16 U^T (L2-resident, 512 KiB).
// ---------------------------------------------------------------------------
__global__ __launch_bounds__(256) void k1_proj(
        const float* __restrict__ x, const short* __restrict__ ut,
        float* __restrict__ r0) {
    int tid  = threadIdx.x;
    int lane = tid & 63;
    int widx = tid >> 6;
    int wg   = blockIdx.x * 4 + widx;      // global wave id, 0..2047
    int rowbase = wg * 16;
    int m  = lane & 15;                    // A row within tile / B col within n-tile
    int kg = lane >> 4;                    // k-group 0..3 (8 k's each)

    const float* xrow = x + (size_t)(rowbase + m) * DMODEL + kg * 8;
    const uint4* utb  = (const uint4*)ut;  // 8 bf16 per uint4
    size_t bidx[4];
#pragma unroll
    for (int nt = 0; nt < 4; nt++) {
        int n = nt * 16 + m;
        bidx[nt] = ((size_t)n * DMODEL + (size_t)(kg * 8)) >> 3;
    }

    f32x4 acc0 = {0,0,0,0}, acc1 = {0,0,0,0}, acc2 = {0,0,0,0}, acc3 = {0,0,0,0};

    for (int kc = 0; kc < DMODEL / 32; kc++) {
        int kb = kc * 32;
        float4 a0 = *(const float4*)(xrow + kb);
        float4 a1 = *(const float4*)(xrow + kb + 4);
        bf16x8 af;
        af[0] = f2bf(a0.x); af[1] = f2bf(a0.y); af[2] = f2bf(a0.z); af[3] = f2bf(a0.w);
        af[4] = f2bf(a1.x); af[5] = f2bf(a1.y); af[6] = f2bf(a1.z); af[7] = f2bf(a1.w);
        size_t ko = (size_t)(kb >> 3);
        bf16x8 b0 = __builtin_bit_cast(bf16x8, utb[bidx[0] + ko]);
        bf16x8 b1 = __builtin_bit_cast(bf16x8, utb[bidx[1] + ko]);
        bf16x8 b2 = __builtin_bit_cast(bf16x8, utb[bidx[2] + ko]);
        bf16x8 b3 = __builtin_bit_cast(bf16x8, utb[bidx[3] + ko]);
        acc0 = __builtin_amdgcn_mfma_f32_16x16x32_bf16(af, b0, acc0, 0, 0, 0);
        acc1 = __builtin_amdgcn_mfma_f32_16x16x32_bf16(af, b1, acc1, 0, 0, 0);
        acc2 = __builtin_amdgcn_mfma_f32_16x16x32_bf16(af, b2, acc2, 0, 0, 0);
        acc3 = __builtin_amdgcn_mfma_f32_16x16x32_bf16(af, b3, acc3, 0, 0, 0);
    }

    // C/D layout (m89/m91 verified): col = lane&15, row = (lane>>4)*4 + reg
    f32x4 accs[4] = {acc0, acc1, acc2, acc3};
#pragma unroll
    for (int nt = 0; nt < 4; nt++) {
#pragma unroll
        for (int i = 0; i < 4; i++) {
            int row = rowbase + kg * 4 + i;
            int col = nt * 16 + m;
            r0[(size_t)row * KSUB + col] = accs[nt][i];
        }
    }
}

// ---------------------------------------------------------------------------
// K2: one wave per row. 5-step scalar recursion in K=64 lane space, then
// stream out = p*x + q*target (float4, coalesced).
// ---------------------------------------------------------------------------
__global__ __launch_bounds__(256) void k2_flow(
        const float* __restrict__ x, const float* __restrict__ r0,
        const float* __restrict__ rm, const float* __restrict__ rt,
        const float* __restrict__ S, const float* __restrict__ tg,
        const float* __restrict__ log_step, const float* __restrict__ sigma,
        const int* __restrict__ nsp, float* __restrict__ out) {
    int tid  = threadIdx.x;
    int lane = tid & 63;
    int widx = tid >> 6;
    int row  = blockIdx.x * 4 + widx;

    float sg = *sigma;
    int   ns = *nsp;
    float step = expf(*log_step);
    step = fminf(fmaxf(step, 1e-3f), 1.0f);
    float h = step / (float)ns;
    float denom = 1.0f / ((float)KSUB * 2.0f * sg * sg);   // TEMPERATURE = 1

    float r0v  = r0[(size_t)row * KSUB + lane];
    float rmv  = rm[lane];
    float rtv  = rt[lane];
    float invS = 1.0f / (S[lane] + 1e-6f);

    float p = 1.0f, q = 0.0f;
    for (int s = 0; s < ns; s++) {
        float v  = (p * r0v + q * rtv - rmv) * invS;
        float ds = v * v;
#pragma unroll
        for (int off = 1; off < 64; off <<= 1)
            ds += __shfl_xor(ds, off, 64);
        float alpha = expf(-ds * denom);
        float ha = h * alpha;
        p = p * (1.0f - ha);
        q = q * (1.0f - ha) + ha;
    }

    const float4* x4 = (const float4*)(x + (size_t)row * DMODEL);
    const float4* t4 = (const float4*)tg;
    float4*       o4 = (float4*)(out + (size_t)row * DMODEL);
#pragma unroll
    for (int i = 0; i < 16; i++) {
        int idx = i * 64 + lane;
        float4 xv = x4[idx];
        float4 tv = t4[idx];
        float4 ov;
        ov.x = p * xv.x + q * tv.x;
        ov.y = p * xv.y + q * tv.y;
        ov.z = p * xv.z + q * tv.z;
        ov.w = p * xv.w + q * tv.w;
        o4[idx] = ov;
    }
}

// ---------------------------------------------------------------------------
extern "C" void kernel_launch(void* const* d_in, const int* in_sizes, int n_in,
                              void* d_out, int out_size, void* d_ws, size_t ws_size,
                              hipStream_t stream) {
    const float* x  = (const float*)d_in[0];
    const float* mu = (const float*)d_in[1];
    const float* U  = (const float*)d_in[2];
    const float* S  = (const float*)d_in[3];
    const float* tg = (const float*)d_in[4];
    const float* ls = (const float*)d_in[5];
    const float* sg = (const float*)d_in[6];
    const int*   ns = (const int*)d_in[7];
    float* out = (float*)d_out;

    char* ws = (char*)d_ws;
    float* rm = (float*)(ws + 0);                                   // 64 f32
    float* rt = (float*)(ws + 256);                                 // 64 f32
    short* ut = (short*)(ws + 1024);                                // 64x4096 bf16 = 512 KiB
    float* r0 = (float*)(ws + 1024 + (size_t)KSUB * DMODEL * 2);    // 32768x64 f32 = 8 MiB

    k0_setup<<<KSUB,      256, 0, stream>>>(U, mu, tg, ut, rm, rt);
    k1_proj <<<BATCH / 64, 256, 0, stream>>>(x, ut, r0);
    k2_flow <<<BATCH / 4,  256, 0, stream>>>(x, r0, rm, rt, S, tg, ls, sg, ns, out);
}